// Round 1
// baseline (235.662 us; speedup 1.0000x reference)
//
#include <hip/hip_runtime.h>
#include <cstring>
#include <cstdint>
#include <cmath>

// Problem constants (fixed by the reference): x is (64, 3, 384, 384) f32.
#define B_IMG 64
#define C_IMG 3
#define H_IMG 384
#define W_IMG 384
#define PLANE (H_IMG * W_IMG)                    // 147456
#define N_TOT (B_IMG * C_IMG * PLANE)            // 28,311,552
#define N4    (N_TOT / 4)                        // 7,077,888
#define V4_PER_BLOCK 512                          // float4s per block (2048 floats; 147456/2048 = 72)
#define BLOCKS (N4 / V4_PER_BLOCK)               // 13824

typedef float nfloat4 __attribute__((ext_vector_type(4)));  // native vec for nontemporal builtins

struct Rect { int t, b, l, r; };        // rows [t,b), cols [l,r); empty if t==b
struct Params { Rect rc[B_IMG]; };      // 1 KB, passed by value as kernarg

__host__ __device__ inline uint32_t rotl32(uint32_t x, uint32_t r) {
  return (x << r) | (x >> (32u - r));
}

// JAX threefry2x32 (20 rounds), bit-exact integer hash.
__host__ __device__ inline void tf2x32(uint32_t k0, uint32_t k1,
                                       uint32_t x0, uint32_t x1,
                                       uint32_t& o0, uint32_t& o1) {
  const uint32_t ks2 = k0 ^ k1 ^ 0x1BD11BDAu;
  x0 += k0; x1 += k1;
  x0 += x1; x1 = rotl32(x1, 13); x1 ^= x0;
  x0 += x1; x1 = rotl32(x1, 15); x1 ^= x0;
  x0 += x1; x1 = rotl32(x1, 26); x1 ^= x0;
  x0 += x1; x1 = rotl32(x1,  6); x1 ^= x0;
  x0 += k1; x1 += ks2 + 1u;
  x0 += x1; x1 = rotl32(x1, 17); x1 ^= x0;
  x0 += x1; x1 = rotl32(x1, 29); x1 ^= x0;
  x0 += x1; x1 = rotl32(x1, 16); x1 ^= x0;
  x0 += x1; x1 = rotl32(x1, 24); x1 ^= x0;
  x0 += ks2; x1 += k0 + 2u;
  x0 += x1; x1 = rotl32(x1, 13); x1 ^= x0;
  x0 += x1; x1 = rotl32(x1, 15); x1 ^= x0;
  x0 += x1; x1 = rotl32(x1, 26); x1 ^= x0;
  x0 += x1; x1 = rotl32(x1,  6); x1 ^= x0;
  x0 += k0; x1 += k1 + 3u;
  x0 += x1; x1 = rotl32(x1, 17); x1 ^= x0;
  x0 += x1; x1 = rotl32(x1, 29); x1 ^= x0;
  x0 += x1; x1 = rotl32(x1, 16); x1 ^= x0;
  x0 += x1; x1 = rotl32(x1, 24); x1 ^= x0;
  x0 += k1; x1 += ks2 + 4u;
  x0 += x1; x1 = rotl32(x1, 13); x1 ^= x0;
  x0 += x1; x1 = rotl32(x1, 15); x1 ^= x0;
  x0 += x1; x1 = rotl32(x1, 26); x1 ^= x0;
  x0 += x1; x1 = rotl32(x1,  6); x1 ^= x0;
  x0 += ks2; x1 += k0 + 5u;
  o0 = x0; o1 = x1;
}

// bits -> float in [0,1): bitcast((bits>>9)|0x3f800000) - 1.0f  (exact)
__host__ __device__ inline float unit_from_bits(uint32_t bits) {
  uint32_t fb = (bits >> 9) | 0x3f800000u;
  float f;
#ifdef __HIP_DEVICE_COMPILE__
  f = __uint_as_float(fb);
#else
  memcpy(&f, &fb, 4);
#endif
  return f - 1.0f;
}

// JAX partitionable-mode random bits for element idx: o0 ^ o1 of tf(key,(0,idx)).
__host__ __device__ inline uint32_t rb_partitionable(uint32_t k0, uint32_t k1, uint32_t idx) {
  uint32_t o0, o1;
  tf2x32(k0, k1, 0u, idx, o0, o1);
  return o0 ^ o1;
}

// sqrt(2) * erfinv(u) matching XLA's f32 ErfInv expansion (Giles polynomial).
// Strict f32 ops (no contraction) so the tail matches the reference.
__device__ inline float noise_val(uint32_t idx, uint32_t kn0, uint32_t kn1) {
  const float LO = -0x1.fffffep-1f;           // nextafter(-1,0)
  uint32_t bits = rb_partitionable(kn0, kn1, idx);
  float f = unit_from_bits(bits);              // [0,1), exact
  float u = __fadd_rn(__fmul_rn(f, 2.0f), LO);
  u = fmaxf(LO, u);
  float t  = __fmul_rn(u, u);
  float wv = -log1pf(-t);
  float p;
  if (wv < 5.0f) {
    float ww = __fadd_rn(wv, -2.5f);
    p = 2.81022636e-08f;
    p = __fadd_rn(__fmul_rn(p, ww),  3.43273939e-07f);
    p = __fadd_rn(__fmul_rn(p, ww), -3.5233877e-06f);
    p = __fadd_rn(__fmul_rn(p, ww), -4.39150654e-06f);
    p = __fadd_rn(__fmul_rn(p, ww),  0.00021858087f);
    p = __fadd_rn(__fmul_rn(p, ww), -0.00125372503f);
    p = __fadd_rn(__fmul_rn(p, ww), -0.00417768164f);
    p = __fadd_rn(__fmul_rn(p, ww),  0.246640727f);
    p = __fadd_rn(__fmul_rn(p, ww),  1.50140941f);
  } else {
    float ww = __fadd_rn(__fsqrt_rn(wv), -3.0f);
    p = -0.000200214257f;
    p = __fadd_rn(__fmul_rn(p, ww),  0.000100950558f);
    p = __fadd_rn(__fmul_rn(p, ww),  0.00134934322f);
    p = __fadd_rn(__fmul_rn(p, ww), -0.00367342844f);
    p = __fadd_rn(__fmul_rn(p, ww),  0.00573950773f);
    p = __fadd_rn(__fmul_rn(p, ww), -0.0076224613f);
    p = __fadd_rn(__fmul_rn(p, ww),  0.00943887047f);
    p = __fadd_rn(__fmul_rn(p, ww),  1.00167406f);
    p = __fadd_rn(__fmul_rn(p, ww),  2.83297682f);
  }
  float r = __fmul_rn(p, u);
  return __fmul_rn(1.41421356237f, r);        // np.float32(np.sqrt(2))
}

// Host-side: derive the 6 subkeys (fold-like split of key(42)) and the 64
// per-sample erase rectangles. Deterministic, identical every call.
static void compute_host_params(Params& P, uint32_t& kn0, uint32_t& kn1) {
#pragma clang fp contract(off)
  uint32_t keys[6][2];  // kp, ka, kr, kt, kl, kn
  for (uint32_t i = 0; i < 6; i++)
    tf2x32(0u, 42u, 0u, i, keys[i][0], keys[i][1]);
  kn0 = keys[5][0]; kn1 = keys[5][1];

  for (int b = 0; b < B_IMG; b++) {
    float u[5];
    for (int k = 0; k < 5; k++)
      u[k] = unit_from_bits(rb_partitionable(keys[k][0], keys[k][1], (uint32_t)b));

    float up = u[0];
    float da = 0.33f - 0.02f;
    float ua = u[1] * da;  ua = ua + 0.02f;  ua = fmaxf(0.02f, ua);
    float ta = ua * 147456.0f;
    float dr = 3.3f - 0.3f;
    float ur = u[2] * dr;  ur = ur + 0.3f;   ur = fmaxf(0.3f, ur);

    int he = (int)rintf(sqrtf(ta * ur));
    int we = (int)rintf(sqrtf(ta / ur));
    bool valid = (up <= 0.5f) && (he < H_IMG) && (we < W_IMG);

    int top  = (int)floorf(u[3] * (float)(H_IMG - he + 1));
    int left = (int)floorf(u[4] * (float)(W_IMG - we + 1));

    if (valid) { P.rc[b].t = top;  P.rc[b].b = top + he; P.rc[b].l = left; P.rc[b].r = left + we; }
    else       { P.rc[b].t = 0;    P.rc[b].b = 0;        P.rc[b].l = 0;    P.rc[b].r = 0; }
  }
}

// ---------------------------------------------------------------------------
// Kernel 1: pure normalize streamer. No rect logic, no noise machinery ->
// minimal VGPR footprint (target <=32 VGPR, 32 waves/CU) so the load queue
// stays full and the kernel runs at copy bandwidth. Same proven R5/MLP=2
// shape: 512 float4/block (2048 floats = 1/72 of a plane, so (b,c) is
// block-uniform), 2 independent nt loads per thread, rcp-FMA, plain stores
// (plain keeps the lines L2-dirty so kernel 2's partial-line overwrites hit
// L2 instead of HBM).
// ---------------------------------------------------------------------------
__global__ __launch_bounds__(256) void norm_kernel(
    const float* __restrict__ x, const float* __restrict__ mean,
    const float* __restrict__ stdv, float* __restrict__ out) {
  const int t = threadIdx.x;
  const int plane = blockIdx.x / (PLANE / (V4_PER_BLOCK * 4));  // / 72, block-uniform
  const int c = plane % C_IMG;

  const nfloat4* __restrict__ x4 = reinterpret_cast<const nfloat4*>(x);
  nfloat4* __restrict__ o4 = reinterpret_cast<nfloat4*>(out);

  const int i0 = blockIdx.x * V4_PER_BLOCK + t;
  const int i1 = i0 + 256;
  const nfloat4 v0 = __builtin_nontemporal_load(&x4[i0]);   // 2 independent
  const nfloat4 v1 = __builtin_nontemporal_load(&x4[i1]);   // loads in flight

  const float m  = mean[c];
  const float rs = 1.0f / stdv[c];
  const float nm = -m * rs;

  nfloat4 o0, o1;
  o0.x = fmaf(v0.x, rs, nm);
  o0.y = fmaf(v0.y, rs, nm);
  o0.z = fmaf(v0.z, rs, nm);
  o0.w = fmaf(v0.w, rs, nm);
  o1.x = fmaf(v1.x, rs, nm);
  o1.y = fmaf(v1.y, rs, nm);
  o1.z = fmaf(v1.z, rs, nm);
  o1.w = fmaf(v1.w, rs, nm);
  o4[i0] = o0;
  o4[i1] = o1;
}

// ---------------------------------------------------------------------------
// Kernel 2: overwrite the erase rectangles with threefry-normal noise.
// Runs after the streamer on the same stream; only touches rect elements
// (~2.5M avg over the batch). grid = (B*C, ROWCHUNKS); each block walks
// rows h = t + blockIdx.y + k*ROWCHUNKS, threads cover columns (row
// segments are contiguous floats -> coalesced within a row). Empty rects
// exit immediately. The heavy erfinv/threefry VGPR cost lives only here.
// ---------------------------------------------------------------------------
#define ROWCHUNKS 16

__global__ __launch_bounds__(256) void erase_patch_kernel(
    float* __restrict__ out, Params P, uint32_t kn0, uint32_t kn1) {
  const int bc = blockIdx.x;            // [0, 192)
  const int b = bc / C_IMG;
  const Rect rc = P.rc[b];
  if (rc.t == rc.b) return;             // no erase for this sample

  const int planeBase = bc * PLANE;
  for (int h = rc.t + blockIdx.y; h < rc.b; h += ROWCHUNKS) {
    const int rowBase = planeBase + h * W_IMG;
    for (int w = rc.l + threadIdx.x; w < rc.r; w += 256) {
      const int idx = rowBase + w;
      out[idx] = noise_val((uint32_t)idx, kn0, kn1);
    }
  }
}

extern "C" void kernel_launch(void* const* d_in, const int* in_sizes, int n_in,
                              void* d_out, int out_size, void* d_ws, size_t ws_size,
                              hipStream_t stream) {
  const float* x    = (const float*)d_in[0];
  const float* mean = (const float*)d_in[1];
  const float* stdv = (const float*)d_in[2];
  float* out = (float*)d_out;

  Params P;
  uint32_t kn0, kn1;
  compute_host_params(P, kn0, kn1);

  norm_kernel<<<BLOCKS, 256, 0, stream>>>(x, mean, stdv, out);
  erase_patch_kernel<<<dim3(B_IMG * C_IMG, ROWCHUNKS), 256, 0, stream>>>(out, P, kn0, kn1);
}

// Round 2
// 231.417 us; speedup vs baseline: 1.0183x; 1.0183x over previous
//
#include <hip/hip_runtime.h>
#include <cstring>
#include <cstdint>
#include <cmath>

// Problem constants (fixed by the reference): x is (64, 3, 384, 384) f32.
#define B_IMG 64
#define C_IMG 3
#define H_IMG 384
#define W_IMG 384
#define PLANE (H_IMG * W_IMG)                    // 147456
#define N_TOT (B_IMG * C_IMG * PLANE)            // 28,311,552
#define N4    (N_TOT / 4)                        // 7,077,888
#define THREADS 256
#define V4_PER_THREAD 16                          // 16 float4 per thread
#define V4_PER_BLOCK (V4_PER_THREAD * THREADS)    // 4096 float4 = 16384 floats
#define BLOCKS (N4 / V4_PER_BLOCK)                // 1728 -> 6912 waves, all co-resident
#define BLOCKS_PER_PLANE (PLANE / (V4_PER_BLOCK * 4))  // 9, exact -> (b,c) block-uniform

typedef float nfloat4 __attribute__((ext_vector_type(4)));  // native vec for nontemporal builtins

struct Rect { int t, b, l, r; };        // rows [t,b), cols [l,r); empty if t==b
struct Params { Rect rc[B_IMG]; };      // 1 KB, passed by value as kernarg

__host__ __device__ inline uint32_t rotl32(uint32_t x, uint32_t r) {
  return (x << r) | (x >> (32u - r));
}

// JAX threefry2x32 (20 rounds), bit-exact integer hash.
__host__ __device__ inline void tf2x32(uint32_t k0, uint32_t k1,
                                       uint32_t x0, uint32_t x1,
                                       uint32_t& o0, uint32_t& o1) {
  const uint32_t ks2 = k0 ^ k1 ^ 0x1BD11BDAu;
  x0 += k0; x1 += k1;
  x0 += x1; x1 = rotl32(x1, 13); x1 ^= x0;
  x0 += x1; x1 = rotl32(x1, 15); x1 ^= x0;
  x0 += x1; x1 = rotl32(x1, 26); x1 ^= x0;
  x0 += x1; x1 = rotl32(x1,  6); x1 ^= x0;
  x0 += k1; x1 += ks2 + 1u;
  x0 += x1; x1 = rotl32(x1, 17); x1 ^= x0;
  x0 += x1; x1 = rotl32(x1, 29); x1 ^= x0;
  x0 += x1; x1 = rotl32(x1, 16); x1 ^= x0;
  x0 += x1; x1 = rotl32(x1, 24); x1 ^= x0;
  x0 += ks2; x1 += k0 + 2u;
  x0 += x1; x1 = rotl32(x1, 13); x1 ^= x0;
  x0 += x1; x1 = rotl32(x1, 15); x1 ^= x0;
  x0 += x1; x1 = rotl32(x1, 26); x1 ^= x0;
  x0 += x1; x1 = rotl32(x1,  6); x1 ^= x0;
  x0 += k0; x1 += k1 + 3u;
  x0 += x1; x1 = rotl32(x1, 17); x1 ^= x0;
  x0 += x1; x1 = rotl32(x1, 29); x1 ^= x0;
  x0 += x1; x1 = rotl32(x1, 16); x1 ^= x0;
  x0 += x1; x1 = rotl32(x1, 24); x1 ^= x0;
  x0 += k1; x1 += ks2 + 4u;
  x0 += x1; x1 = rotl32(x1, 13); x1 ^= x0;
  x0 += x1; x1 = rotl32(x1, 15); x1 ^= x0;
  x0 += x1; x1 = rotl32(x1, 26); x1 ^= x0;
  x0 += x1; x1 = rotl32(x1,  6); x1 ^= x0;
  x0 += ks2; x1 += k0 + 5u;
  o0 = x0; o1 = x1;
}

// bits -> float in [0,1): bitcast((bits>>9)|0x3f800000) - 1.0f  (exact)
__host__ __device__ inline float unit_from_bits(uint32_t bits) {
  uint32_t fb = (bits >> 9) | 0x3f800000u;
  float f;
#ifdef __HIP_DEVICE_COMPILE__
  f = __uint_as_float(fb);
#else
  memcpy(&f, &fb, 4);
#endif
  return f - 1.0f;
}

// JAX partitionable-mode random bits for element idx: o0 ^ o1 of tf(key,(0,idx)).
__host__ __device__ inline uint32_t rb_partitionable(uint32_t k0, uint32_t k1, uint32_t idx) {
  uint32_t o0, o1;
  tf2x32(k0, k1, 0u, idx, o0, o1);
  return o0 ^ o1;
}

// sqrt(2) * erfinv(u) matching XLA's f32 ErfInv expansion (Giles polynomial).
// Strict f32 ops (no contraction) so the tail matches the reference.
__device__ inline float noise_val(uint32_t idx, uint32_t kn0, uint32_t kn1) {
  const float LO = -0x1.fffffep-1f;           // nextafter(-1,0)
  uint32_t bits = rb_partitionable(kn0, kn1, idx);
  float f = unit_from_bits(bits);              // [0,1), exact
  float u = __fadd_rn(__fmul_rn(f, 2.0f), LO);
  u = fmaxf(LO, u);
  float t  = __fmul_rn(u, u);
  float wv = -log1pf(-t);
  float p;
  if (wv < 5.0f) {
    float ww = __fadd_rn(wv, -2.5f);
    p = 2.81022636e-08f;
    p = __fadd_rn(__fmul_rn(p, ww),  3.43273939e-07f);
    p = __fadd_rn(__fmul_rn(p, ww), -3.5233877e-06f);
    p = __fadd_rn(__fmul_rn(p, ww), -4.39150654e-06f);
    p = __fadd_rn(__fmul_rn(p, ww),  0.00021858087f);
    p = __fadd_rn(__fmul_rn(p, ww), -0.00125372503f);
    p = __fadd_rn(__fmul_rn(p, ww), -0.00417768164f);
    p = __fadd_rn(__fmul_rn(p, ww),  0.246640727f);
    p = __fadd_rn(__fmul_rn(p, ww),  1.50140941f);
  } else {
    float ww = __fadd_rn(__fsqrt_rn(wv), -3.0f);
    p = -0.000200214257f;
    p = __fadd_rn(__fmul_rn(p, ww),  0.000100950558f);
    p = __fadd_rn(__fmul_rn(p, ww),  0.00134934322f);
    p = __fadd_rn(__fmul_rn(p, ww), -0.00367342844f);
    p = __fadd_rn(__fmul_rn(p, ww),  0.00573950773f);
    p = __fadd_rn(__fmul_rn(p, ww), -0.0076224613f);
    p = __fadd_rn(__fmul_rn(p, ww),  0.00943887047f);
    p = __fadd_rn(__fmul_rn(p, ww),  1.00167406f);
    p = __fadd_rn(__fmul_rn(p, ww),  2.83297682f);
  }
  float r = __fmul_rn(p, u);
  return __fmul_rn(1.41421356237f, r);        // np.float32(np.sqrt(2))
}

// Host-side: derive the 6 subkeys (fold-like split of key(42)) and the 64
// per-sample erase rectangles. Deterministic, identical every call.
static void compute_host_params(Params& P, uint32_t& kn0, uint32_t& kn1) {
#pragma clang fp contract(off)
  uint32_t keys[6][2];  // kp, ka, kr, kt, kl, kn
  for (uint32_t i = 0; i < 6; i++)
    tf2x32(0u, 42u, 0u, i, keys[i][0], keys[i][1]);
  kn0 = keys[5][0]; kn1 = keys[5][1];

  for (int b = 0; b < B_IMG; b++) {
    float u[5];
    for (int k = 0; k < 5; k++)
      u[k] = unit_from_bits(rb_partitionable(keys[k][0], keys[k][1], (uint32_t)b));

    float up = u[0];
    float da = 0.33f - 0.02f;
    float ua = u[1] * da;  ua = ua + 0.02f;  ua = fmaxf(0.02f, ua);
    float ta = ua * 147456.0f;
    float dr = 3.3f - 0.3f;
    float ur = u[2] * dr;  ur = ur + 0.3f;   ur = fmaxf(0.3f, ur);

    int he = (int)rintf(sqrtf(ta * ur));
    int we = (int)rintf(sqrtf(ta / ur));
    bool valid = (up <= 0.5f) && (he < H_IMG) && (we < W_IMG);

    int top  = (int)floorf(u[3] * (float)(H_IMG - he + 1));
    int left = (int)floorf(u[4] * (float)(W_IMG - we + 1));

    if (valid) { P.rc[b].t = top;  P.rc[b].b = top + he; P.rc[b].l = left; P.rc[b].r = left + we; }
    else       { P.rc[b].t = 0;    P.rc[b].b = 0;        P.rc[b].l = 0;    P.rc[b].r = 0; }
  }
}

// ---------------------------------------------------------------------------
// Fused persistent-block streamer (R2 shape change; noise path unchanged
// from the proven 198.7us kernel).
//   - 1728 blocks x 256 threads, 16 float4/thread, exact partition of N4.
//     All 6912 waves co-resident (launch_bounds(256,8) -> <=64 VGPR) -> no
//     block launch/retire churn; each wave streams 32 KB.
//   - Block covers 4096 consecutive float4s = exactly 1/9 of a plane ->
//     (b,c) block-uniform, rect in SGPRs.
//   - Inner loop: 4 independent nt loads issued before any use (27 loads
//     in flight per SIMD in steady state), rcp-FMA normalize, plain stores
//     (full 1KB-contiguous wave stores -> no RMW fetch).
// ---------------------------------------------------------------------------
__global__ __launch_bounds__(256, 8) void erase_norm_kernel(
    const float* __restrict__ x, const float* __restrict__ mean,
    const float* __restrict__ stdv, float* __restrict__ out,
    Params P, uint32_t kn0, uint32_t kn1) {
  const int t = threadIdx.x;
  const int bid = blockIdx.x;
  const int plane = bid / BLOCKS_PER_PLANE;   // /9, block-uniform
  const int c = plane % C_IMG;
  const int b = plane / C_IMG;

  const nfloat4* __restrict__ x4 = reinterpret_cast<const nfloat4*>(x);
  nfloat4* __restrict__ o4 = reinterpret_cast<nfloat4*>(out);

  const float m  = mean[c];
  const float rs = 1.0f / stdv[c];
  const float nm = -m * rs;
  const Rect rc = P.rc[b];
  const int planeBase = plane * PLANE;
  const int base4 = bid * V4_PER_BLOCK + t;

  for (int jj = 0; jj < V4_PER_THREAD; jj += 4) {
    nfloat4 v[4];
    int idx[4];
#pragma unroll
    for (int k = 0; k < 4; k++) {
      idx[k] = base4 + (jj + k) * THREADS;
      v[k] = __builtin_nontemporal_load(&x4[idx[k]]);   // 4 independent loads in flight
    }
#pragma unroll
    for (int k = 0; k < 4; k++) {
      nfloat4 o;
      o.x = fmaf(v[k].x, rs, nm);
      o.y = fmaf(v[k].y, rs, nm);
      o.z = fmaf(v[k].z, rs, nm);
      o.w = fmaf(v[k].w, rs, nm);

      const int base = idx[k] * 4;
      const int rel  = base - planeBase;      // [0, 147456)
      const int h = rel / W_IMG;
      const int w = rel - h * W_IMG;
      if (h >= rc.t && h < rc.b && w < rc.r && (w + 3) >= rc.l) {
        if (w     >= rc.l && w     < rc.r) o.x = noise_val((uint32_t)(base + 0), kn0, kn1);
        if (w + 1 >= rc.l && w + 1 < rc.r) o.y = noise_val((uint32_t)(base + 1), kn0, kn1);
        if (w + 2 >= rc.l && w + 2 < rc.r) o.z = noise_val((uint32_t)(base + 2), kn0, kn1);
        if (w + 3 >= rc.l && w + 3 < rc.r) o.w = noise_val((uint32_t)(base + 3), kn0, kn1);
      }
      o4[idx[k]] = o;                         // plain store through L2
    }
  }
}

extern "C" void kernel_launch(void* const* d_in, const int* in_sizes, int n_in,
                              void* d_out, int out_size, void* d_ws, size_t ws_size,
                              hipStream_t stream) {
  const float* x    = (const float*)d_in[0];
  const float* mean = (const float*)d_in[1];
  const float* stdv = (const float*)d_in[2];
  float* out = (float*)d_out;

  Params P;
  uint32_t kn0, kn1;
  compute_host_params(P, kn0, kn1);

  erase_norm_kernel<<<BLOCKS, THREADS, 0, stream>>>(x, mean, stdv, out, P, kn0, kn1);
}

// Round 3
// 207.967 us; speedup vs baseline: 1.1332x; 1.1128x over previous
//
#include <hip/hip_runtime.h>
#include <cstring>
#include <cstdint>
#include <cmath>

// Problem constants (fixed by the reference): x is (64, 3, 384, 384) f32.
#define B_IMG 64
#define C_IMG 3
#define H_IMG 384
#define W_IMG 384
#define PLANE (H_IMG * W_IMG)                    // 147456
#define N_TOT (B_IMG * C_IMG * PLANE)            // 28,311,552
#define N4    (N_TOT / 4)                        // 7,077,888
#define V4_PER_BLOCK 512                          // float4s per block (2048 floats; 147456/2048 = 72)
#define BLOCKS (N4 / V4_PER_BLOCK)               // 13824

typedef float nfloat4 __attribute__((ext_vector_type(4)));  // native vec for nontemporal builtins

struct Rect { int t, b, l, r; };        // rows [t,b), cols [l,r); empty if t==b
struct Params { Rect rc[B_IMG]; };      // 1 KB, passed by value as kernarg

__host__ __device__ inline uint32_t rotl32(uint32_t x, uint32_t r) {
  return (x << r) | (x >> (32u - r));
}

// JAX threefry2x32 (20 rounds), bit-exact integer hash.
__host__ __device__ inline void tf2x32(uint32_t k0, uint32_t k1,
                                       uint32_t x0, uint32_t x1,
                                       uint32_t& o0, uint32_t& o1) {
  const uint32_t ks2 = k0 ^ k1 ^ 0x1BD11BDAu;
  x0 += k0; x1 += k1;
  x0 += x1; x1 = rotl32(x1, 13); x1 ^= x0;
  x0 += x1; x1 = rotl32(x1, 15); x1 ^= x0;
  x0 += x1; x1 = rotl32(x1, 26); x1 ^= x0;
  x0 += x1; x1 = rotl32(x1,  6); x1 ^= x0;
  x0 += k1; x1 += ks2 + 1u;
  x0 += x1; x1 = rotl32(x1, 17); x1 ^= x0;
  x0 += x1; x1 = rotl32(x1, 29); x1 ^= x0;
  x0 += x1; x1 = rotl32(x1, 16); x1 ^= x0;
  x0 += x1; x1 = rotl32(x1, 24); x1 ^= x0;
  x0 += ks2; x1 += k0 + 2u;
  x0 += x1; x1 = rotl32(x1, 13); x1 ^= x0;
  x0 += x1; x1 = rotl32(x1, 15); x1 ^= x0;
  x0 += x1; x1 = rotl32(x1, 26); x1 ^= x0;
  x0 += x1; x1 = rotl32(x1,  6); x1 ^= x0;
  x0 += k0; x1 += k1 + 3u;
  x0 += x1; x1 = rotl32(x1, 17); x1 ^= x0;
  x0 += x1; x1 = rotl32(x1, 29); x1 ^= x0;
  x0 += x1; x1 = rotl32(x1, 16); x1 ^= x0;
  x0 += x1; x1 = rotl32(x1, 24); x1 ^= x0;
  x0 += k1; x1 += ks2 + 4u;
  x0 += x1; x1 = rotl32(x1, 13); x1 ^= x0;
  x0 += x1; x1 = rotl32(x1, 15); x1 ^= x0;
  x0 += x1; x1 = rotl32(x1, 26); x1 ^= x0;
  x0 += x1; x1 = rotl32(x1,  6); x1 ^= x0;
  x0 += ks2; x1 += k0 + 5u;
  o0 = x0; o1 = x1;
}

// bits -> float in [0,1): bitcast((bits>>9)|0x3f800000) - 1.0f  (exact)
__host__ __device__ inline float unit_from_bits(uint32_t bits) {
  uint32_t fb = (bits >> 9) | 0x3f800000u;
  float f;
#ifdef __HIP_DEVICE_COMPILE__
  f = __uint_as_float(fb);
#else
  memcpy(&f, &fb, 4);
#endif
  return f - 1.0f;
}

// JAX partitionable-mode random bits for element idx: o0 ^ o1 of tf(key,(0,idx)).
__host__ __device__ inline uint32_t rb_partitionable(uint32_t k0, uint32_t k1, uint32_t idx) {
  uint32_t o0, o1;
  tf2x32(k0, k1, 0u, idx, o0, o1);
  return o0 ^ o1;
}

// sqrt(2) * erfinv(u) matching XLA's f32 ErfInv expansion (Giles polynomial).
// Strict f32 ops (no contraction) so the tail matches the reference.
__device__ inline float noise_val(uint32_t idx, uint32_t kn0, uint32_t kn1) {
  const float LO = -0x1.fffffep-1f;           // nextafter(-1,0)
  uint32_t bits = rb_partitionable(kn0, kn1, idx);
  float f = unit_from_bits(bits);              // [0,1), exact
  float u = __fadd_rn(__fmul_rn(f, 2.0f), LO);
  u = fmaxf(LO, u);
  float t  = __fmul_rn(u, u);
  float wv = -log1pf(-t);
  float p;
  if (wv < 5.0f) {
    float ww = __fadd_rn(wv, -2.5f);
    p = 2.81022636e-08f;
    p = __fadd_rn(__fmul_rn(p, ww),  3.43273939e-07f);
    p = __fadd_rn(__fmul_rn(p, ww), -3.5233877e-06f);
    p = __fadd_rn(__fmul_rn(p, ww), -4.39150654e-06f);
    p = __fadd_rn(__fmul_rn(p, ww),  0.00021858087f);
    p = __fadd_rn(__fmul_rn(p, ww), -0.00125372503f);
    p = __fadd_rn(__fmul_rn(p, ww), -0.00417768164f);
    p = __fadd_rn(__fmul_rn(p, ww),  0.246640727f);
    p = __fadd_rn(__fmul_rn(p, ww),  1.50140941f);
  } else {
    float ww = __fadd_rn(__fsqrt_rn(wv), -3.0f);
    p = -0.000200214257f;
    p = __fadd_rn(__fmul_rn(p, ww),  0.000100950558f);
    p = __fadd_rn(__fmul_rn(p, ww),  0.00134934322f);
    p = __fadd_rn(__fmul_rn(p, ww), -0.00367342844f);
    p = __fadd_rn(__fmul_rn(p, ww),  0.00573950773f);
    p = __fadd_rn(__fmul_rn(p, ww), -0.0076224613f);
    p = __fadd_rn(__fmul_rn(p, ww),  0.00943887047f);
    p = __fadd_rn(__fmul_rn(p, ww),  1.00167406f);
    p = __fadd_rn(__fmul_rn(p, ww),  2.83297682f);
  }
  float r = __fmul_rn(p, u);
  return __fmul_rn(1.41421356237f, r);        // np.float32(np.sqrt(2))
}

// Host-side: derive the 6 subkeys (fold-like split of key(42)) and the 64
// per-sample erase rectangles. Deterministic, identical every call.
static void compute_host_params(Params& P, uint32_t& kn0, uint32_t& kn1) {
#pragma clang fp contract(off)
  uint32_t keys[6][2];  // kp, ka, kr, kt, kl, kn
  for (uint32_t i = 0; i < 6; i++)
    tf2x32(0u, 42u, 0u, i, keys[i][0], keys[i][1]);
  kn0 = keys[5][0]; kn1 = keys[5][1];

  for (int b = 0; b < B_IMG; b++) {
    float u[5];
    for (int k = 0; k < 5; k++)
      u[k] = unit_from_bits(rb_partitionable(keys[k][0], keys[k][1], (uint32_t)b));

    float up = u[0];
    float da = 0.33f - 0.02f;
    float ua = u[1] * da;  ua = ua + 0.02f;  ua = fmaxf(0.02f, ua);
    float ta = ua * 147456.0f;
    float dr = 3.3f - 0.3f;
    float ur = u[2] * dr;  ur = ur + 0.3f;   ur = fmaxf(0.3f, ur);

    int he = (int)rintf(sqrtf(ta * ur));
    int we = (int)rintf(sqrtf(ta / ur));
    bool valid = (up <= 0.5f) && (he < H_IMG) && (we < W_IMG);

    int top  = (int)floorf(u[3] * (float)(H_IMG - he + 1));
    int left = (int)floorf(u[4] * (float)(W_IMG - we + 1));

    if (valid) { P.rc[b].t = top;  P.rc[b].b = top + he; P.rc[b].l = left; P.rc[b].r = left + we; }
    else       { P.rc[b].t = 0;    P.rc[b].b = 0;        P.rc[b].l = 0;    P.rc[b].r = 0; }
  }
}

// R3: exact R0 shape (known-best 198.7us config: 13824 blocks x 256 thr,
// MLP=2, 512 float4/block -> (b,c) block-uniform), with ONLY the cache
// hints flipped to match the data-flow:
//   - x is re-read every rep -> PLAIN (temporal) loads so it stays
//     LLC-resident (R2 counters: nt loads left FETCH_SIZE at 55MB = half
//     of x re-fetched from HBM every rep).
//   - out is single-use -> NONTEMPORAL stores so the 110MB output stream
//     doesn't flush x out of L2/LLC.
__global__ __launch_bounds__(256) void erase_norm_kernel(
    const float* __restrict__ x, const float* __restrict__ mean,
    const float* __restrict__ stdv, float* __restrict__ out,
    Params P, uint32_t kn0, uint32_t kn1) {
  const int t = threadIdx.x;
  const int plane = blockIdx.x / (PLANE / (V4_PER_BLOCK * 4));  // / 72, block-uniform
  const int c = plane % C_IMG;
  const int b = plane / C_IMG;

  const nfloat4* __restrict__ x4 = reinterpret_cast<const nfloat4*>(x);
  nfloat4* __restrict__ o4 = reinterpret_cast<nfloat4*>(out);

  const int i0 = blockIdx.x * V4_PER_BLOCK + t;
  const int i1 = i0 + 256;
  const nfloat4 v0 = x4[i0];               // plain loads: keep x in LLC
  const nfloat4 v1 = x4[i1];               // (2 independent loads in flight)

  const float m  = mean[c];
  const float rs = 1.0f / stdv[c];
  const float nm = -m * rs;
  const Rect rc = P.rc[b];
  const int planeBase = plane * PLANE;

  nfloat4 vv[2] = {v0, v1};
  int idx4[2] = {i0, i1};
#pragma unroll
  for (int j = 0; j < 2; j++) {
    nfloat4 o;
    o.x = fmaf(vv[j].x, rs, nm);
    o.y = fmaf(vv[j].y, rs, nm);
    o.z = fmaf(vv[j].z, rs, nm);
    o.w = fmaf(vv[j].w, rs, nm);

    const int base = idx4[j] * 4;
    const int rel  = base - planeBase;      // [0, 147456)
    const int h = rel / W_IMG;
    const int w = rel - h * W_IMG;
    if (h >= rc.t && h < rc.b && w < rc.r && (w + 3) >= rc.l) {
      if (w     >= rc.l && w     < rc.r) o.x = noise_val((uint32_t)(base + 0), kn0, kn1);
      if (w + 1 >= rc.l && w + 1 < rc.r) o.y = noise_val((uint32_t)(base + 1), kn0, kn1);
      if (w + 2 >= rc.l && w + 2 < rc.r) o.z = noise_val((uint32_t)(base + 2), kn0, kn1);
      if (w + 3 >= rc.l && w + 3 < rc.r) o.w = noise_val((uint32_t)(base + 3), kn0, kn1);
    }
    __builtin_nontemporal_store(o, &o4[idx4[j]]);   // stream out past L2/LLC
  }
}

extern "C" void kernel_launch(void* const* d_in, const int* in_sizes, int n_in,
                              void* d_out, int out_size, void* d_ws, size_t ws_size,
                              hipStream_t stream) {
  const float* x    = (const float*)d_in[0];
  const float* mean = (const float*)d_in[1];
  const float* stdv = (const float*)d_in[2];
  float* out = (float*)d_out;

  Params P;
  uint32_t kn0, kn1;
  compute_host_params(P, kn0, kn1);

  erase_norm_kernel<<<BLOCKS, 256, 0, stream>>>(x, mean, stdv, out, P, kn0, kn1);
}

// Round 4
// 203.891 us; speedup vs baseline: 1.1558x; 1.0200x over previous
//
#include <hip/hip_runtime.h>
#include <cstring>
#include <cstdint>
#include <cmath>

// Problem constants (fixed by the reference): x is (64, 3, 384, 384) f32.
#define B_IMG 64
#define C_IMG 3
#define H_IMG 384
#define W_IMG 384
#define PLANE (H_IMG * W_IMG)                    // 147456
#define N_TOT (B_IMG * C_IMG * PLANE)            // 28,311,552
#define N4    (N_TOT / 4)                        // 7,077,888
#define THREADS 256
#define V4_PER_BLOCK 1024                         // float4s per block (4096 floats; 147456/4096 = 36)
#define BLOCKS (N4 / V4_PER_BLOCK)               // 6912
#define BLOCKS_PER_PLANE (PLANE / (V4_PER_BLOCK * 4))  // 36, exact -> (b,c) block-uniform

typedef float nfloat4 __attribute__((ext_vector_type(4)));  // native vec for nontemporal builtins

struct Rect { int t, b, l, r; };        // rows [t,b), cols [l,r); empty if t==b
struct Params { Rect rc[B_IMG]; };      // 1 KB, passed by value as kernarg

__host__ __device__ inline uint32_t rotl32(uint32_t x, uint32_t r) {
  return (x << r) | (x >> (32u - r));
}

// JAX threefry2x32 (20 rounds), bit-exact integer hash.
__host__ __device__ inline void tf2x32(uint32_t k0, uint32_t k1,
                                       uint32_t x0, uint32_t x1,
                                       uint32_t& o0, uint32_t& o1) {
  const uint32_t ks2 = k0 ^ k1 ^ 0x1BD11BDAu;
  x0 += k0; x1 += k1;
  x0 += x1; x1 = rotl32(x1, 13); x1 ^= x0;
  x0 += x1; x1 = rotl32(x1, 15); x1 ^= x0;
  x0 += x1; x1 = rotl32(x1, 26); x1 ^= x0;
  x0 += x1; x1 = rotl32(x1,  6); x1 ^= x0;
  x0 += k1; x1 += ks2 + 1u;
  x0 += x1; x1 = rotl32(x1, 17); x1 ^= x0;
  x0 += x1; x1 = rotl32(x1, 29); x1 ^= x0;
  x0 += x1; x1 = rotl32(x1, 16); x1 ^= x0;
  x0 += x1; x1 = rotl32(x1, 24); x1 ^= x0;
  x0 += ks2; x1 += k0 + 2u;
  x0 += x1; x1 = rotl32(x1, 13); x1 ^= x0;
  x0 += x1; x1 = rotl32(x1, 15); x1 ^= x0;
  x0 += x1; x1 = rotl32(x1, 26); x1 ^= x0;
  x0 += x1; x1 = rotl32(x1,  6); x1 ^= x0;
  x0 += k0; x1 += k1 + 3u;
  x0 += x1; x1 = rotl32(x1, 17); x1 ^= x0;
  x0 += x1; x1 = rotl32(x1, 29); x1 ^= x0;
  x0 += x1; x1 = rotl32(x1, 16); x1 ^= x0;
  x0 += x1; x1 = rotl32(x1, 24); x1 ^= x0;
  x0 += k1; x1 += ks2 + 4u;
  x0 += x1; x1 = rotl32(x1, 13); x1 ^= x0;
  x0 += x1; x1 = rotl32(x1, 15); x1 ^= x0;
  x0 += x1; x1 = rotl32(x1, 26); x1 ^= x0;
  x0 += x1; x1 = rotl32(x1,  6); x1 ^= x0;
  x0 += ks2; x1 += k0 + 5u;
  o0 = x0; o1 = x1;
}

// bits -> float in [0,1): bitcast((bits>>9)|0x3f800000) - 1.0f  (exact)
__host__ __device__ inline float unit_from_bits(uint32_t bits) {
  uint32_t fb = (bits >> 9) | 0x3f800000u;
  float f;
#ifdef __HIP_DEVICE_COMPILE__
  f = __uint_as_float(fb);
#else
  memcpy(&f, &fb, 4);
#endif
  return f - 1.0f;
}

// JAX partitionable-mode random bits for element idx: o0 ^ o1 of tf(key,(0,idx)).
__host__ __device__ inline uint32_t rb_partitionable(uint32_t k0, uint32_t k1, uint32_t idx) {
  uint32_t o0, o1;
  tf2x32(k0, k1, 0u, idx, o0, o1);
  return o0 ^ o1;
}

// sqrt(2) * erfinv(u) matching XLA's f32 ErfInv expansion (Giles polynomial).
// Strict f32 ops (no contraction) so the tail matches the reference.
__device__ inline float noise_val(uint32_t idx, uint32_t kn0, uint32_t kn1) {
  const float LO = -0x1.fffffep-1f;           // nextafter(-1,0)
  uint32_t bits = rb_partitionable(kn0, kn1, idx);
  float f = unit_from_bits(bits);              // [0,1), exact
  float u = __fadd_rn(__fmul_rn(f, 2.0f), LO);
  u = fmaxf(LO, u);
  float t  = __fmul_rn(u, u);
  float wv = -log1pf(-t);
  float p;
  if (wv < 5.0f) {
    float ww = __fadd_rn(wv, -2.5f);
    p = 2.81022636e-08f;
    p = __fadd_rn(__fmul_rn(p, ww),  3.43273939e-07f);
    p = __fadd_rn(__fmul_rn(p, ww), -3.5233877e-06f);
    p = __fadd_rn(__fmul_rn(p, ww), -4.39150654e-06f);
    p = __fadd_rn(__fmul_rn(p, ww),  0.00021858087f);
    p = __fadd_rn(__fmul_rn(p, ww), -0.00125372503f);
    p = __fadd_rn(__fmul_rn(p, ww), -0.00417768164f);
    p = __fadd_rn(__fmul_rn(p, ww),  0.246640727f);
    p = __fadd_rn(__fmul_rn(p, ww),  1.50140941f);
  } else {
    float ww = __fadd_rn(__fsqrt_rn(wv), -3.0f);
    p = -0.000200214257f;
    p = __fadd_rn(__fmul_rn(p, ww),  0.000100950558f);
    p = __fadd_rn(__fmul_rn(p, ww),  0.00134934322f);
    p = __fadd_rn(__fmul_rn(p, ww), -0.00367342844f);
    p = __fadd_rn(__fmul_rn(p, ww),  0.00573950773f);
    p = __fadd_rn(__fmul_rn(p, ww), -0.0076224613f);
    p = __fadd_rn(__fmul_rn(p, ww),  0.00943887047f);
    p = __fadd_rn(__fmul_rn(p, ww),  1.00167406f);
    p = __fadd_rn(__fmul_rn(p, ww),  2.83297682f);
  }
  float r = __fmul_rn(p, u);
  return __fmul_rn(1.41421356237f, r);        // np.float32(np.sqrt(2))
}

// Host-side: derive the 6 subkeys (fold-like split of key(42)) and the 64
// per-sample erase rectangles. Deterministic, identical every call.
static void compute_host_params(Params& P, uint32_t& kn0, uint32_t& kn1) {
#pragma clang fp contract(off)
  uint32_t keys[6][2];  // kp, ka, kr, kt, kl, kn
  for (uint32_t i = 0; i < 6; i++)
    tf2x32(0u, 42u, 0u, i, keys[i][0], keys[i][1]);
  kn0 = keys[5][0]; kn1 = keys[5][1];

  for (int b = 0; b < B_IMG; b++) {
    float u[5];
    for (int k = 0; k < 5; k++)
      u[k] = unit_from_bits(rb_partitionable(keys[k][0], keys[k][1], (uint32_t)b));

    float up = u[0];
    float da = 0.33f - 0.02f;
    float ua = u[1] * da;  ua = ua + 0.02f;  ua = fmaxf(0.02f, ua);
    float ta = ua * 147456.0f;
    float dr = 3.3f - 0.3f;
    float ur = u[2] * dr;  ur = ur + 0.3f;   ur = fmaxf(0.3f, ur);

    int he = (int)rintf(sqrtf(ta * ur));
    int we = (int)rintf(sqrtf(ta / ur));
    bool valid = (up <= 0.5f) && (he < H_IMG) && (we < W_IMG);

    int top  = (int)floorf(u[3] * (float)(H_IMG - he + 1));
    int left = (int)floorf(u[4] * (float)(W_IMG - we + 1));

    if (valid) { P.rc[b].t = top;  P.rc[b].b = top + he; P.rc[b].l = left; P.rc[b].r = left + we; }
    else       { P.rc[b].t = 0;    P.rc[b].b = 0;        P.rc[b].l = 0;    P.rc[b].r = 0; }
  }
}

// R4: R0's proven config (nt loads + plain stores, 256 threads, contiguous
// 1KB wave accesses, (b,c) block-uniform) with ONE variable changed:
// MLP 2 -> 4. Each thread issues 4 independent nt float4 loads before any
// use (i0, +256, +512, +768); 1024 float4/block -> 6912 blocks (36/plane).
// Probes the residual latency component of the ~2.3 TB/s mixed-stream wall
// (R2: 2.07 TB/s @27.8% occ, R3: 2.26 @54% -> +11% for 2x occupancy).
__global__ __launch_bounds__(256) void erase_norm_kernel(
    const float* __restrict__ x, const float* __restrict__ mean,
    const float* __restrict__ stdv, float* __restrict__ out,
    Params P, uint32_t kn0, uint32_t kn1) {
  const int t = threadIdx.x;
  const int bid = blockIdx.x;
  const int plane = bid / BLOCKS_PER_PLANE;   // /36, block-uniform
  const int c = plane % C_IMG;
  const int b = plane / C_IMG;

  const nfloat4* __restrict__ x4 = reinterpret_cast<const nfloat4*>(x);
  nfloat4* __restrict__ o4 = reinterpret_cast<nfloat4*>(out);

  const int base4 = bid * V4_PER_BLOCK + t;

  nfloat4 v[4];
  int idx4[4];
#pragma unroll
  for (int j = 0; j < 4; j++) {
    idx4[j] = base4 + j * THREADS;
    v[j] = __builtin_nontemporal_load(&x4[idx4[j]]);   // 4 independent loads in flight
  }

  const float m  = mean[c];
  const float rs = 1.0f / stdv[c];
  const float nm = -m * rs;
  const Rect rc = P.rc[b];
  const int planeBase = plane * PLANE;

#pragma unroll
  for (int j = 0; j < 4; j++) {
    nfloat4 o;
    o.x = fmaf(v[j].x, rs, nm);
    o.y = fmaf(v[j].y, rs, nm);
    o.z = fmaf(v[j].z, rs, nm);
    o.w = fmaf(v[j].w, rs, nm);

    const int base = idx4[j] * 4;
    const int rel  = base - planeBase;      // [0, 147456)
    const int h = rel / W_IMG;
    const int w = rel - h * W_IMG;
    if (h >= rc.t && h < rc.b && w < rc.r && (w + 3) >= rc.l) {
      if (w     >= rc.l && w     < rc.r) o.x = noise_val((uint32_t)(base + 0), kn0, kn1);
      if (w + 1 >= rc.l && w + 1 < rc.r) o.y = noise_val((uint32_t)(base + 1), kn0, kn1);
      if (w + 2 >= rc.l && w + 2 < rc.r) o.z = noise_val((uint32_t)(base + 2), kn0, kn1);
      if (w + 3 >= rc.l && w + 3 < rc.r) o.w = noise_val((uint32_t)(base + 3), kn0, kn1);
    }
    o4[idx4[j]] = o;                        // plain store through L2 (proven best)
  }
}

extern "C" void kernel_launch(void* const* d_in, const int* in_sizes, int n_in,
                              void* d_out, int out_size, void* d_ws, size_t ws_size,
                              hipStream_t stream) {
  const float* x    = (const float*)d_in[0];
  const float* mean = (const float*)d_in[1];
  const float* stdv = (const float*)d_in[2];
  float* out = (float*)d_out;

  Params P;
  uint32_t kn0, kn1;
  compute_host_params(P, kn0, kn1);

  erase_norm_kernel<<<BLOCKS, THREADS, 0, stream>>>(x, mean, stdv, out, P, kn0, kn1);
}

// Round 5
// 198.554 us; speedup vs baseline: 1.1869x; 1.0269x over previous
//
#include <hip/hip_runtime.h>
#include <cstring>
#include <cstdint>
#include <cmath>

// Problem constants (fixed by the reference): x is (64, 3, 384, 384) f32.
#define B_IMG 64
#define C_IMG 3
#define H_IMG 384
#define W_IMG 384
#define PLANE (H_IMG * W_IMG)                    // 147456
#define N_TOT (B_IMG * C_IMG * PLANE)            // 28,311,552
#define N4    (N_TOT / 4)                        // 7,077,888
#define V4_PER_BLOCK 512                          // float4s per block (2048 floats; 147456/2048 = 72)
#define BLOCKS (N4 / V4_PER_BLOCK)               // 13824

typedef float nfloat4 __attribute__((ext_vector_type(4)));  // native vec for nontemporal builtins

struct Rect { int t, b, l, r; };        // rows [t,b), cols [l,r); empty if t==b
struct Params { Rect rc[B_IMG]; };      // 1 KB, passed by value as kernarg

__host__ __device__ inline uint32_t rotl32(uint32_t x, uint32_t r) {
  return (x << r) | (x >> (32u - r));
}

// JAX threefry2x32 (20 rounds), bit-exact integer hash.
__host__ __device__ inline void tf2x32(uint32_t k0, uint32_t k1,
                                       uint32_t x0, uint32_t x1,
                                       uint32_t& o0, uint32_t& o1) {
  const uint32_t ks2 = k0 ^ k1 ^ 0x1BD11BDAu;
  x0 += k0; x1 += k1;
  x0 += x1; x1 = rotl32(x1, 13); x1 ^= x0;
  x0 += x1; x1 = rotl32(x1, 15); x1 ^= x0;
  x0 += x1; x1 = rotl32(x1, 26); x1 ^= x0;
  x0 += x1; x1 = rotl32(x1,  6); x1 ^= x0;
  x0 += k1; x1 += ks2 + 1u;
  x0 += x1; x1 = rotl32(x1, 17); x1 ^= x0;
  x0 += x1; x1 = rotl32(x1, 29); x1 ^= x0;
  x0 += x1; x1 = rotl32(x1, 16); x1 ^= x0;
  x0 += x1; x1 = rotl32(x1, 24); x1 ^= x0;
  x0 += ks2; x1 += k0 + 2u;
  x0 += x1; x1 = rotl32(x1, 13); x1 ^= x0;
  x0 += x1; x1 = rotl32(x1, 15); x1 ^= x0;
  x0 += x1; x1 = rotl32(x1, 26); x1 ^= x0;
  x0 += x1; x1 = rotl32(x1,  6); x1 ^= x0;
  x0 += k0; x1 += k1 + 3u;
  x0 += x1; x1 = rotl32(x1, 17); x1 ^= x0;
  x0 += x1; x1 = rotl32(x1, 29); x1 ^= x0;
  x0 += x1; x1 = rotl32(x1, 16); x1 ^= x0;
  x0 += x1; x1 = rotl32(x1, 24); x1 ^= x0;
  x0 += k1; x1 += ks2 + 4u;
  x0 += x1; x1 = rotl32(x1, 13); x1 ^= x0;
  x0 += x1; x1 = rotl32(x1, 15); x1 ^= x0;
  x0 += x1; x1 = rotl32(x1, 26); x1 ^= x0;
  x0 += x1; x1 = rotl32(x1,  6); x1 ^= x0;
  x0 += ks2; x1 += k0 + 5u;
  o0 = x0; o1 = x1;
}

// bits -> float in [0,1): bitcast((bits>>9)|0x3f800000) - 1.0f  (exact)
__host__ __device__ inline float unit_from_bits(uint32_t bits) {
  uint32_t fb = (bits >> 9) | 0x3f800000u;
  float f;
#ifdef __HIP_DEVICE_COMPILE__
  f = __uint_as_float(fb);
#else
  memcpy(&f, &fb, 4);
#endif
  return f - 1.0f;
}

// JAX partitionable-mode random bits for element idx: o0 ^ o1 of tf(key,(0,idx)).
__host__ __device__ inline uint32_t rb_partitionable(uint32_t k0, uint32_t k1, uint32_t idx) {
  uint32_t o0, o1;
  tf2x32(k0, k1, 0u, idx, o0, o1);
  return o0 ^ o1;
}

// sqrt(2) * erfinv(u) matching XLA's f32 ErfInv expansion (Giles polynomial).
// Strict f32 ops (no contraction) so the tail matches the reference.
__device__ inline float noise_val(uint32_t idx, uint32_t kn0, uint32_t kn1) {
  const float LO = -0x1.fffffep-1f;           // nextafter(-1,0)
  uint32_t bits = rb_partitionable(kn0, kn1, idx);
  float f = unit_from_bits(bits);              // [0,1), exact
  float u = __fadd_rn(__fmul_rn(f, 2.0f), LO);
  u = fmaxf(LO, u);
  float t  = __fmul_rn(u, u);
  float wv = -log1pf(-t);
  float p;
  if (wv < 5.0f) {
    float ww = __fadd_rn(wv, -2.5f);
    p = 2.81022636e-08f;
    p = __fadd_rn(__fmul_rn(p, ww),  3.43273939e-07f);
    p = __fadd_rn(__fmul_rn(p, ww), -3.5233877e-06f);
    p = __fadd_rn(__fmul_rn(p, ww), -4.39150654e-06f);
    p = __fadd_rn(__fmul_rn(p, ww),  0.00021858087f);
    p = __fadd_rn(__fmul_rn(p, ww), -0.00125372503f);
    p = __fadd_rn(__fmul_rn(p, ww), -0.00417768164f);
    p = __fadd_rn(__fmul_rn(p, ww),  0.246640727f);
    p = __fadd_rn(__fmul_rn(p, ww),  1.50140941f);
  } else {
    float ww = __fadd_rn(__fsqrt_rn(wv), -3.0f);
    p = -0.000200214257f;
    p = __fadd_rn(__fmul_rn(p, ww),  0.000100950558f);
    p = __fadd_rn(__fmul_rn(p, ww),  0.00134934322f);
    p = __fadd_rn(__fmul_rn(p, ww), -0.00367342844f);
    p = __fadd_rn(__fmul_rn(p, ww),  0.00573950773f);
    p = __fadd_rn(__fmul_rn(p, ww), -0.0076224613f);
    p = __fadd_rn(__fmul_rn(p, ww),  0.00943887047f);
    p = __fadd_rn(__fmul_rn(p, ww),  1.00167406f);
    p = __fadd_rn(__fmul_rn(p, ww),  2.83297682f);
  }
  float r = __fmul_rn(p, u);
  return __fmul_rn(1.41421356237f, r);        // np.float32(np.sqrt(2))
}

// Host-side: derive the 6 subkeys (fold-like split of key(42)) and the 64
// per-sample erase rectangles. Deterministic, identical every call.
static void compute_host_params(Params& P, uint32_t& kn0, uint32_t& kn1) {
#pragma clang fp contract(off)
  uint32_t keys[6][2];  // kp, ka, kr, kt, kl, kn
  for (uint32_t i = 0; i < 6; i++)
    tf2x32(0u, 42u, 0u, i, keys[i][0], keys[i][1]);
  kn0 = keys[5][0]; kn1 = keys[5][1];

  for (int b = 0; b < B_IMG; b++) {
    float u[5];
    for (int k = 0; k < 5; k++)
      u[k] = unit_from_bits(rb_partitionable(keys[k][0], keys[k][1], (uint32_t)b));

    float up = u[0];
    float da = 0.33f - 0.02f;
    float ua = u[1] * da;  ua = ua + 0.02f;  ua = fmaxf(0.02f, ua);
    float ta = ua * 147456.0f;
    float dr = 3.3f - 0.3f;
    float ur = u[2] * dr;  ur = ur + 0.3f;   ur = fmaxf(0.3f, ur);

    int he = (int)rintf(sqrtf(ta * ur));
    int we = (int)rintf(sqrtf(ta / ur));
    bool valid = (up <= 0.5f) && (he < H_IMG) && (we < W_IMG);

    int top  = (int)floorf(u[3] * (float)(H_IMG - he + 1));
    int left = (int)floorf(u[4] * (float)(W_IMG - we + 1));

    if (valid) { P.rc[b].t = top;  P.rc[b].b = top + he; P.rc[b].l = left; P.rc[b].r = left + we; }
    else       { P.rc[b].t = 0;    P.rc[b].b = 0;        P.rc[b].l = 0;    P.rc[b].r = 0; }
  }
}

// R5: R0-exact config (13824 blocks x 256 thr, MLP=2, nt loads, plain
// stores -- the proven-best 198.7us shape) + ONE change: a block-uniform
// rect early-out. A block covers 2048 consecutive floats of one plane =
// rows [h0, hN] (block-uniform scalars). If that row range misses the
// sample's rect (~84% of blocks: half the images have no rect; rects
// average ~30% of rows), take a pure stream path with zero per-element
// rect math and zero divergence. Targets the 35% VALUBusy / issue-port
// interleave seen in R2/R3 counters.
__global__ __launch_bounds__(256) void erase_norm_kernel(
    const float* __restrict__ x, const float* __restrict__ mean,
    const float* __restrict__ stdv, float* __restrict__ out,
    Params P, uint32_t kn0, uint32_t kn1) {
  const int t = threadIdx.x;
  const int bid = blockIdx.x;
  const int plane = bid / (PLANE / (V4_PER_BLOCK * 4));  // / 72, block-uniform
  const int c = plane % C_IMG;
  const int b = plane / C_IMG;

  const nfloat4* __restrict__ x4 = reinterpret_cast<const nfloat4*>(x);
  nfloat4* __restrict__ o4 = reinterpret_cast<nfloat4*>(out);

  const int i0 = bid * V4_PER_BLOCK + t;
  const int i1 = i0 + 256;
  const nfloat4 v0 = __builtin_nontemporal_load(&x4[i0]);   // 2 independent
  const nfloat4 v1 = __builtin_nontemporal_load(&x4[i1]);   // loads in flight

  const float m  = mean[c];
  const float rs = 1.0f / stdv[c];
  const float nm = -m * rs;
  const Rect rc = P.rc[b];
  const int planeBase = plane * PLANE;

  // Block-uniform row range of this block's 2048 floats within its plane.
  const int blockStart = bid * (V4_PER_BLOCK * 4) - planeBase;   // [0, PLANE)
  const int h0 = blockStart / W_IMG;                              // scalar
  const int hN = (blockStart + V4_PER_BLOCK * 4 - 1) / W_IMG;     // scalar

  nfloat4 o0, o1;
  o0.x = fmaf(v0.x, rs, nm);
  o0.y = fmaf(v0.y, rs, nm);
  o0.z = fmaf(v0.z, rs, nm);
  o0.w = fmaf(v0.w, rs, nm);
  o1.x = fmaf(v1.x, rs, nm);
  o1.y = fmaf(v1.y, rs, nm);
  o1.z = fmaf(v1.z, rs, nm);
  o1.w = fmaf(v1.w, rs, nm);

  // Scalar (wave-uniform) branch: most blocks never touch a rect.
  if (rc.b > rc.t && hN >= rc.t && h0 < rc.b) {
    nfloat4 vv[2] = {o0, o1};
    int idx4[2] = {i0, i1};
#pragma unroll
    for (int j = 0; j < 2; j++) {
      nfloat4 o = vv[j];
      const int base = idx4[j] * 4;
      const int rel  = base - planeBase;      // [0, 147456)
      const int h = rel / W_IMG;
      const int w = rel - h * W_IMG;
      if (h >= rc.t && h < rc.b && w < rc.r && (w + 3) >= rc.l) {
        if (w     >= rc.l && w     < rc.r) o.x = noise_val((uint32_t)(base + 0), kn0, kn1);
        if (w + 1 >= rc.l && w + 1 < rc.r) o.y = noise_val((uint32_t)(base + 1), kn0, kn1);
        if (w + 2 >= rc.l && w + 2 < rc.r) o.z = noise_val((uint32_t)(base + 2), kn0, kn1);
        if (w + 3 >= rc.l && w + 3 < rc.r) o.w = noise_val((uint32_t)(base + 3), kn0, kn1);
      }
      o4[idx4[j]] = o;                        // plain store (proven best)
    }
  } else {
    // Pure stream path: no per-element rect math, no divergence.
    o4[i0] = o0;
    o4[i1] = o1;
  }
}

extern "C" void kernel_launch(void* const* d_in, const int* in_sizes, int n_in,
                              void* d_out, int out_size, void* d_ws, size_t ws_size,
                              hipStream_t stream) {
  const float* x    = (const float*)d_in[0];
  const float* mean = (const float*)d_in[1];
  const float* stdv = (const float*)d_in[2];
  float* out = (float*)d_out;

  Params P;
  uint32_t kn0, kn1;
  compute_host_params(P, kn0, kn1);

  erase_norm_kernel<<<BLOCKS, 256, 0, stream>>>(x, mean, stdv, out, P, kn0, kn1);
}